// Round 7
// baseline (258.948 us; speedup 1.0000x reference)
//
#include <hip/hip_runtime.h>
#include <hip/hip_bf16.h>

typedef unsigned short u16;
typedef unsigned int   u32;

using bf16x8 = __attribute__((ext_vector_type(8))) short;  // 8 bf16 in 4 VGPRs
using f32x4  = __attribute__((ext_vector_type(4))) float;  // MFMA accumulator

#define NB 32
#define NP 1024
#define ND 256

__device__ __forceinline__ u16 f2bf(float x){
  u32 u = __float_as_uint(x);
  u += 0x7FFFu + ((u >> 16) & 1u);   // round-to-nearest-even
  return (u16)(u >> 16);
}

__device__ __forceinline__ float bf2f(u16 x){
  return __uint_as_float((u32)x << 16);
}

__device__ __forceinline__ void glds16(const void* g, void* l){
  __builtin_amdgcn_global_load_lds((const __attribute__((address_space(1))) void*)g,
                                   (__attribute__((address_space(3))) void*)l, 16, 0, 0);
}

// ---------------- prep 1: Pbf = bf16(P), sbv[row] = P[row,:] . wb ----------------
__global__ void prep_rows(const float* __restrict__ P, const float* __restrict__ wi,
                          u16* __restrict__ Pbf, float* __restrict__ sbv){
  const int row  = blockIdx.x * 4 + (threadIdx.x >> 6);   // one wave per row
  const int lane = threadIdx.x & 63;
  const float4 p  = *(const float4*)(P  + (size_t)row * ND + lane * 4);
  const float4 wb = *(const float4*)(wi + ND + lane * 4);  // wb = wi[256:512]
  ushort4 pb;
  pb.x = f2bf(p.x); pb.y = f2bf(p.y); pb.z = f2bf(p.z); pb.w = f2bf(p.w);
  *(ushort4*)(Pbf + (size_t)row * ND + lane * 4) = pb;
  float s = p.x*wb.x + p.y*wb.y + p.z*wb.z + p.w*wb.w;
  #pragma unroll
  for (int m = 1; m < 64; m <<= 1) s += __shfl_xor(s, m, 64);
  if (lane == 0) sbv[row] = s;
}

// ------- prep 2: pack W fragment-major: Wp[((t*16+c)*64+lane)*8 + e] -------------
__global__ void prep_w(const float* __restrict__ w1, const float* __restrict__ w2,
                       const float* __restrict__ w3, u16* __restrict__ Wp){
  const int t = blockIdx.x;                       // 0..47
  const float* w = (t < 16) ? w1 : ((t < 32) ? w2 : w3);
  const int tid = threadIdx.x;
  #pragma unroll
  for (int j = 0; j < 4; ++j){
    int item = tid + 256 * j;                     // c*64 + lane
    int c = item >> 6, lane = item & 63;
    int ncol = ((t & 15) << 4) + (lane & 15);
    int k0 = 32 * c + 8 * (lane >> 4);
    u16 tmp[8];
    #pragma unroll
    for (int e = 0; e < 8; ++e) tmp[e] = f2bf(w[(size_t)(k0 + e) * 256 + ncol]);
    *(uint4*)(Wp + ((size_t)(t * 16 + c) * 64 + lane) * 8) = *(uint4*)tmp;
  }
}

// ---------------- prep 3: PbfT[b][d][j] = Pbf[b][j][d] (64x64 LDS tiles) ---------
__global__ void transpose_p(const u16* __restrict__ Pbf, u16* __restrict__ PbfT){
  const int b = blockIdx.z, jt = blockIdx.x, dt = blockIdx.y;
  __shared__ u16 T[64][72];
  const int tid = threadIdx.x;
  #pragma unroll
  for (int it = 0; it < 2; ++it){
    int cc = tid + 256 * it;               // 0..511: 64 j-rows x 8 chunks
    int j = cc >> 3, c8 = cc & 7;
    uint4 v = *(const uint4*)(Pbf + ((size_t)b * NP + jt * 64 + j) * ND + dt * 64 + c8 * 8);
    *(uint4*)&T[j][c8 * 8] = v;
  }
  __syncthreads();
  #pragma unroll
  for (int it = 0; it < 2; ++it){
    int cc = tid + 256 * it;               // 64 d-rows x 8 chunks
    int d = cc >> 3, c8 = cc & 7;
    u16 tmp[8];
    #pragma unroll
    for (int k = 0; k < 8; ++k) tmp[k] = T[c8 * 8 + k][d];
    *(uint4*)(PbfT + ((size_t)b * ND + dt * 64 + d) * NP + jt * 64 + c8 * 8) = *(uint4*)tmp;
  }
}

// ---------------- attention: QBLK=64 (4 waves), KBLK=64, K-only LDS --------------
// K LDS (single buffer, 32 KB): phys = ck*1024 + 16*(j ^ ((ck&1)<<4)), ck = 16B
// d-chunk 0..31, j = key 0..63 (r4-measured conflict-free, both-sides swizzle).
// V frags read DIRECT from L2-resident PbfT (no LDS staging): per-lane 16B
// contiguous, 16 independent PV MFMAs + 12 waves/CU hide the L2 latency.
// LDS/block 42 KB -> 3 blocks/CU (vs 2): the round-3..6 plateau was stall-bound
// at 2 waves/SIMD; this buys 3 waves/SIMD + halves per-key fixed costs vs r6.
__launch_bounds__(256, 3)
__global__ void attn_kernel(const float* __restrict__ P, const float* __restrict__ wi,
                            const u16* __restrict__ Pbf, const u16* __restrict__ PbfT,
                            const float* __restrict__ sbv, u16* __restrict__ attnb){
  const int p    = blockIdx.x;
  const int bid  = ((p & 7) << 6) | (p >> 3);     // 64 consecutive bids per XCD
  const int b    = bid >> 4;
  const int q0   = (bid & 15) << 6;
  const int tid  = threadIdx.x;
  const int wave = tid >> 6, lane = tid & 63, lo = lane & 15, hi = lane >> 4;

  __shared__ __align__(16) u16 KtA[64 * 256];     // 32 KB, single buffer
  __shared__ __align__(16) u16 Sp[4][16][72];     // per-wave P repack (9 KB)
  char* KtB = (char*)KtA;

  // ---- Q fragments (A-operand): q = P * wc, bf16, in regs ----
  bf16x8 qf[8];
  {
    const int qrow = q0 + wave * 16 + lo;
    const float* prow = P  + ((size_t)b * NP + qrow) * ND;
    const float* wcp  = wi + 512;
    #pragma unroll
    for (int c = 0; c < 8; ++c){
      const int d0 = 32 * c + 8 * hi;
      float4 a  = *(const float4*)(prow + d0);
      float4 a2 = *(const float4*)(prow + d0 + 4);
      float4 wa  = *(const float4*)(wcp + d0);
      float4 wa2 = *(const float4*)(wcp + d0 + 4);
      bf16x8 q;
      q[0]=(short)f2bf(a.x*wa.x);  q[1]=(short)f2bf(a.y*wa.y);
      q[2]=(short)f2bf(a.z*wa.z);  q[3]=(short)f2bf(a.w*wa.w);
      q[4]=(short)f2bf(a2.x*wa2.x); q[5]=(short)f2bf(a2.y*wa2.y);
      q[6]=(short)f2bf(a2.z*wa2.z); q[7]=(short)f2bf(a2.w*wa2.w);
      qf[c] = q;
    }
  }

  f32x4 of[16];
  #pragma unroll
  for (int t = 0; t < 16; ++t) of[t] = (f32x4){0.f,0.f,0.f,0.f};
  float mx[4] = {-1e30f,-1e30f,-1e30f,-1e30f};
  float ls[4] = {0.f,0.f,0.f,0.f};

  const u16* kslab = Pbf + (size_t)b * NP * ND;                  // [j][d] row-major
  const u16* vbase = PbfT + ((size_t)b * ND + lo) * NP + 8 * hi; // lane's V^T base

  for (int kt = 0; kt < 16; ++kt){
    const int kbase = kt * 64;

    // ---- stage K tile (32 KB, 8 glds rounds); source pre-swizzled ----
    #pragma unroll
    for (int it = 0; it < 8; ++it){
      int off = it * 4096 + tid * 16;             // physical LDS byte
      int ck  = off >> 10;                        // 16B d-chunk
      int row = ((off >> 4) & 63) ^ ((ck & 1) << 4);
      glds16((const char*)(kslab + (size_t)(kbase + row) * ND + ck * 8), KtB + off);
    }
    float sbc[4];
    #pragma unroll
    for (int nt = 0; nt < 4; ++nt) sbc[nt] = sbv[(size_t)b * NP + kbase + nt * 16 + lo];
    __syncthreads();   // drains glds vmcnt: K tile visible

    // ---- S = Q K^T (4 col-tiles of 16 keys) ----
    f32x4 s[4];
    #pragma unroll
    for (int nt = 0; nt < 4; ++nt){
      f32x4 acc = (f32x4){0.f,0.f,0.f,0.f};
      #pragma unroll
      for (int c = 0; c < 8; ++c){
        int ck = 4 * c + hi;
        int ad = ck * 1024 + ((((nt << 4) + lo) ^ ((ck & 1) << 4)) << 4);
        bf16x8 kf = *(const bf16x8*)(KtB + ad);
        acc = __builtin_amdgcn_mfma_f32_16x16x32_bf16(qf[c], kf, acc, 0, 0, 0);
      }
      s[nt] = acc;
      float sv = sbc[nt];
      #pragma unroll
      for (int r = 0; r < 4; ++r) s[nt][r] += sv;
    }

    // ---- deferred online softmax ----
    float md = -1e30f;
    #pragma unroll
    for (int nt = 0; nt < 4; ++nt)
      #pragma unroll
      for (int r = 0; r < 4; ++r) md = fmaxf(md, s[nt][r] - mx[r]);
    if (!__all(md <= 8.f)){
      // slow path: proper row maxima + rescale (tile 0, rare after)
      float scale[4];
      #pragma unroll
      for (int r = 0; r < 4; ++r){
        float v = fmaxf(fmaxf(s[0][r], s[1][r]), fmaxf(s[2][r], s[3][r]));
        v = fmaxf(v, __shfl_xor(v, 1, 64));
        v = fmaxf(v, __shfl_xor(v, 2, 64));
        v = fmaxf(v, __shfl_xor(v, 4, 64));
        v = fmaxf(v, __shfl_xor(v, 8, 64));
        float mnew = fmaxf(mx[r], v);
        scale[r] = __expf(mx[r] - mnew);
        mx[r] = mnew;
        ls[r] *= scale[r];
      }
      #pragma unroll
      for (int t = 0; t < 16; ++t)
        #pragma unroll
        for (int r = 0; r < 4; ++r) of[t][r] *= scale[r];
    }
    // common path: exp, per-lane partial sums, repack (p bounded by e^8)
    #pragma unroll
    for (int nt = 0; nt < 4; ++nt)
      #pragma unroll
      for (int r = 0; r < 4; ++r){
        float pv = __expf(s[nt][r] - mx[r]);
        ls[r] += pv;
        Sp[wave][4 * hi + r][16 * nt + lo] = f2bf(pv);
      }

    // ---- O += P V : V frags direct from global (L2-resident PbfT) ----
    #pragma unroll
    for (int kk = 0; kk < 2; ++kk){
      bf16x8 pa = *(const bf16x8*)&Sp[wave][lo][32 * kk + 8 * hi];
      #pragma unroll
      for (int t = 0; t < 16; ++t){
        bf16x8 vb = *(const bf16x8*)(vbase + (size_t)t * 16 * NP + kbase + 32 * kk);
        of[t] = __builtin_amdgcn_mfma_f32_16x16x32_bf16(pa, vb, of[t], 0, 0, 0);
      }
    }
    __syncthreads();   // all waves done reading K before next stage overwrites
  }

  // ---- epilogue: one cross-lane ls reduce, O /= l, store bf16 ----
  #pragma unroll
  for (int r = 0; r < 4; ++r){
    ls[r] += __shfl_xor(ls[r], 1, 64);
    ls[r] += __shfl_xor(ls[r], 2, 64);
    ls[r] += __shfl_xor(ls[r], 4, 64);
    ls[r] += __shfl_xor(ls[r], 8, 64);
  }
  const int qrow = q0 + wave * 16;
  #pragma unroll
  for (int t = 0; t < 16; ++t){
    #pragma unroll
    for (int r = 0; r < 4; ++r){
      float o = of[t][r] / ls[r];
      attnb[((size_t)b * NP + qrow + 4 * hi + r) * ND + 16 * t + lo] = f2bf(o);
    }
  }
}

// ---------------- MLP: proper GEMM, M-tile 128, fused gate epilogue --------------
// NOTE: acc[3][8] = 96 VGPRs of accumulator. __launch_bounds__ min-waves MUST stay
// at 2 (VGPR budget 256): round-5's (256,4) capped the allocator at 64 VGPR and
// spilled all accumulators to scratch (WRITE_SIZE 33 -> 325 MB, 18 -> 136 us).
__launch_bounds__(256, 2)
__global__ void mlp_kernel(const u16* __restrict__ Pbf, const u16* __restrict__ attnb,
                           const u16* __restrict__ Wp,
                           const float* __restrict__ b1, const float* __restrict__ b2,
                           const float* __restrict__ b3, float* __restrict__ out){
  const int p    = blockIdx.x;
  const int swz  = ((p & 7) << 7) | (p >> 3);     // XCD-chunked
  const int mt   = swz >> 2, cg = swz & 3;
  const int tid  = threadIdx.x;
  const int wave = tid >> 6, lane = tid & 63, lo = lane & 15, hi = lane >> 4;
  const int tq   = 4 * cg + wave;
  const int m0   = mt * 128;

  __shared__ __align__(16) u16 Ab[2][128 * 64];   // 2 x 16 KB, swizzled

  f32x4 acc[3][8];
  #pragma unroll
  for (int e = 0; e < 3; ++e)
    #pragma unroll
    for (int m = 0; m < 8; ++m) acc[e][m] = (f32x4){0.f,0.f,0.f,0.f};

  auto stage = [&](int s, int buf){
    const u16* xs = (s < 4) ? (Pbf   + (size_t)m0 * ND + s * 64)
                            : (attnb + (size_t)m0 * ND + (s - 4) * 64);
    char* dst = (char*)Ab[buf];
    #pragma unroll
    for (int it = 0; it < 4; ++it){
      int off = it * 4096 + wave * 1024 + lane * 16;   // physical LDS byte
      int row = off >> 7;                               // 128B per row
      int cl  = (off & 127) ^ ((row & 7) << 4);         // logical byte in row
      glds16((const char*)(xs + (size_t)row * ND) + cl, dst + it * 4096 + wave * 1024);
    }
  };

  stage(0, 0);
  __syncthreads();

  for (int s = 0; s < 8; ++s){
    if (s < 7) stage(s + 1, (s + 1) & 1);
    const char* ab = (const char*)Ab[s & 1];
    #pragma unroll
    for (int cc = 0; cc < 2; ++cc){
      const int c = 2 * s + cc;
      bf16x8 wf[3];
      #pragma unroll
      for (int e = 0; e < 3; ++e)
        wf[e] = *(const bf16x8*)(Wp + ((size_t)((tq + 16 * e) * 16 + c) * 64 + lane) * 8);
      #pragma unroll
      for (int m = 0; m < 8; ++m){
        int row = 16 * m + lo;
        bf16x8 af = *(const bf16x8*)(ab + row * 128 + ((64 * cc + 16 * hi) ^ ((row & 7) << 4)));
        #pragma unroll
        for (int e = 0; e < 3; ++e)
          acc[e][m] = __builtin_amdgcn_mfma_f32_16x16x32_bf16(af, wf[e], acc[e][m], 0, 0, 0);
      }
    }
    __syncthreads();
  }

  // ---- fused gate epilogue ----
  const int d = 16 * tq + lo;
  const float bb1 = b1[d], bb2 = b2[d], bb3 = b3[d];
  #pragma unroll
  for (int m = 0; m < 8; ++m){
    #pragma unroll
    for (int r = 0; r < 4; ++r){
      const int row = m0 + 16 * m + 4 * hi + r;
      float y1 = acc[0][m][r] + bb1;
      float y2 = acc[1][m][r] + bb2;
      float y3 = acc[2][m][r] + bb3;
      float pv = bf2f(Pbf[(size_t)row * ND + d]);
      float e2 = __expf(2.f * y1);
      float z  = (e2 - 1.f) / (e2 + 1.f);          // tanh
      float rr = 1.f / (1.f + __expf(-y2));        // sigmoid
      float ff = 1.f / (1.f + __expf(-y3));        // sigmoid
      out[(size_t)row * ND + d] = rr * pv + ff * z;
    }
  }
}

extern "C" void kernel_launch(void* const* d_in, const int* in_sizes, int n_in,
                              void* d_out, int out_size, void* d_ws, size_t ws_size,
                              hipStream_t stream){
  const float* P  = (const float*)d_in[0];
  const float* wi = (const float*)d_in[1];
  const float* w1 = (const float*)d_in[2];
  const float* w2 = (const float*)d_in[3];
  const float* w3 = (const float*)d_in[4];
  const float* b1 = (const float*)d_in[5];
  const float* b2 = (const float*)d_in[6];
  const float* b3 = (const float*)d_in[7];
  float* out = (float*)d_out;

  char* ws = (char*)d_ws;
  u16*   Pbf   = (u16*)  (ws);                        // 16 MB
  u16*   PbfT  = (u16*)  (ws + (16u << 20));          // 16 MB
  u16*   attnb = (u16*)  (ws + (32u << 20));          // 16 MB
  u16*   Wp    = (u16*)  (ws + (48u << 20));          // 768 KB packed fragments
  float* sbv   = (float*)(ws + (49u << 20));          // 128 KB

  prep_rows<<<8192, 256, 0, stream>>>(P, wi, Pbf, sbv);
  prep_w<<<48, 256, 0, stream>>>(w1, w2, w3, Wp);
  transpose_p<<<dim3(16, 4, 32), 256, 0, stream>>>(Pbf, PbfT);
  attn_kernel<<<512, 256, 0, stream>>>(P, wi, Pbf, PbfT, sbv, attnb);
  mlp_kernel<<<1024, 256, 0, stream>>>(Pbf, attnb, Wp, b1, b2, b3, out);
}

// Round 8
// 250.087 us; speedup vs baseline: 1.0354x; 1.0354x over previous
//
#include <hip/hip_runtime.h>
#include <hip/hip_bf16.h>

typedef unsigned short u16;
typedef unsigned int   u32;

using bf16x8 = __attribute__((ext_vector_type(8))) short;  // 8 bf16 in 4 VGPRs
using f32x4  = __attribute__((ext_vector_type(4))) float;  // MFMA accumulator

#define NB 32
#define NP 1024
#define ND 256

__device__ __forceinline__ u16 f2bf(float x){
  u32 u = __float_as_uint(x);
  u += 0x7FFFu + ((u >> 16) & 1u);   // round-to-nearest-even
  return (u16)(u >> 16);
}

__device__ __forceinline__ float bf2f(u16 x){
  return __uint_as_float((u32)x << 16);
}

__device__ __forceinline__ void glds16(const void* g, void* l){
  __builtin_amdgcn_global_load_lds((const __attribute__((address_space(1))) void*)g,
                                   (__attribute__((address_space(3))) void*)l, 16, 0, 0);
}

// ---------------- prep 1: Pbf = bf16(P), sbv[row] = P[row,:] . wb ----------------
__global__ void prep_rows(const float* __restrict__ P, const float* __restrict__ wi,
                          u16* __restrict__ Pbf, float* __restrict__ sbv){
  const int row  = blockIdx.x * 4 + (threadIdx.x >> 6);   // one wave per row
  const int lane = threadIdx.x & 63;
  const float4 p  = *(const float4*)(P  + (size_t)row * ND + lane * 4);
  const float4 wb = *(const float4*)(wi + ND + lane * 4);  // wb = wi[256:512]
  ushort4 pb;
  pb.x = f2bf(p.x); pb.y = f2bf(p.y); pb.z = f2bf(p.z); pb.w = f2bf(p.w);
  *(ushort4*)(Pbf + (size_t)row * ND + lane * 4) = pb;
  float s = p.x*wb.x + p.y*wb.y + p.z*wb.z + p.w*wb.w;
  #pragma unroll
  for (int m = 1; m < 64; m <<= 1) s += __shfl_xor(s, m, 64);
  if (lane == 0) sbv[row] = s;
}

// ------- prep 2: pack W fragment-major: Wp[((t*16+c)*64+lane)*8 + e] -------------
__global__ void prep_w(const float* __restrict__ w1, const float* __restrict__ w2,
                       const float* __restrict__ w3, u16* __restrict__ Wp){
  const int t = blockIdx.x;                       // 0..47
  const float* w = (t < 16) ? w1 : ((t < 32) ? w2 : w3);
  const int tid = threadIdx.x;
  #pragma unroll
  for (int j = 0; j < 4; ++j){
    int item = tid + 256 * j;                     // c*64 + lane
    int c = item >> 6, lane = item & 63;
    int ncol = ((t & 15) << 4) + (lane & 15);
    int k0 = 32 * c + 8 * (lane >> 4);
    u16 tmp[8];
    #pragma unroll
    for (int e = 0; e < 8; ++e) tmp[e] = f2bf(w[(size_t)(k0 + e) * 256 + ncol]);
    *(uint4*)(Wp + ((size_t)(t * 16 + c) * 64 + lane) * 8) = *(uint4*)tmp;
  }
}

// ---------------- prep 3: PbfT[b][d][j] = Pbf[b][j][d] (64x64 LDS tiles) ---------
__global__ void transpose_p(const u16* __restrict__ Pbf, u16* __restrict__ PbfT){
  const int b = blockIdx.z, jt = blockIdx.x, dt = blockIdx.y;
  __shared__ u16 T[64][72];
  const int tid = threadIdx.x;
  #pragma unroll
  for (int it = 0; it < 2; ++it){
    int cc = tid + 256 * it;               // 0..511: 64 j-rows x 8 chunks
    int j = cc >> 3, c8 = cc & 7;
    uint4 v = *(const uint4*)(Pbf + ((size_t)b * NP + jt * 64 + j) * ND + dt * 64 + c8 * 8);
    *(uint4*)&T[j][c8 * 8] = v;
  }
  __syncthreads();
  #pragma unroll
  for (int it = 0; it < 2; ++it){
    int cc = tid + 256 * it;               // 64 d-rows x 8 chunks
    int d = cc >> 3, c8 = cc & 7;
    u16 tmp[8];
    #pragma unroll
    for (int k = 0; k < 8; ++k) tmp[k] = T[c8 * 8 + k][d];
    *(uint4*)(PbfT + ((size_t)b * ND + dt * 64 + d) * NP + jt * 64 + c8 * 8) = *(uint4*)tmp;
  }
}

// ---------------- attention: QBLK=64 (4 waves), KBLK=64, reg-staged LDS ----------
// Staging is global->VGPR (coalesced: 8 rows x 128B per wave-instr = 16 lines)
// then ds_write_b128 into the r4-verified conflict-free layouts:
//   K: phys = ck*1024 + 16*(j ^ ((ck&1)<<4)), ck = 16B d-chunk 0..31, j = 0..63
//   V: phys = c*4096  + 16*(d ^ ((c&1)<<4)),  c  = 16B j-chunk 0..7,  d = 0..255
// Write-side banks: per 16-lane phase, j&7 (resp d&7) = lane&7 covers all 8
// quad-groups x2 -> conflict-free. Loads for tile t+1 issue before compute(t)
// (T14 async split: HBM/L2 latency hides under MFMA); single-buffered, 73 KB,
// 2 blocks/CU. NOTE: global_load_lds is NOT used here - its linear dest forced
// a 64-line scattered source (the r2-r6 hidden stall, ~4000 cyc/tile).
__launch_bounds__(256, 2)
__global__ void attn_kernel(const float* __restrict__ P, const float* __restrict__ wi,
                            const u16* __restrict__ Pbf, const u16* __restrict__ PbfT,
                            const float* __restrict__ sbv, u16* __restrict__ attnb){
  const int p    = blockIdx.x;
  const int bid  = ((p & 7) << 6) | (p >> 3);     // 64 consecutive bids per XCD
  const int b    = bid >> 4;
  const int q0   = (bid & 15) << 6;
  const int tid  = threadIdx.x;
  const int wave = tid >> 6, lane = tid & 63, lo = lane & 15, hi = lane >> 4;
  const int l7   = lane & 7,  l3 = lane >> 3;     // stage coords

  __shared__ __align__(16) u16 KtA[64 * 256];     // 32 KB
  __shared__ __align__(16) u16 VtA[256 * 64];     // 32 KB
  __shared__ __align__(16) u16 Sp[4][16][72];     // 9 KB
  char* KtB = (char*)KtA;
  char* VtB = (char*)VtA;

  // ---- Q fragments (A-operand): q = P * wc, bf16, in regs ----
  bf16x8 qf[8];
  {
    const int qrow = q0 + wave * 16 + lo;
    const float* prow = P  + ((size_t)b * NP + qrow) * ND;
    const float* wcp  = wi + 512;
    #pragma unroll
    for (int c = 0; c < 8; ++c){
      const int d0 = 32 * c + 8 * hi;
      float4 a  = *(const float4*)(prow + d0);
      float4 a2 = *(const float4*)(prow + d0 + 4);
      float4 wa  = *(const float4*)(wcp + d0);
      float4 wa2 = *(const float4*)(wcp + d0 + 4);
      bf16x8 q;
      q[0]=(short)f2bf(a.x*wa.x);  q[1]=(short)f2bf(a.y*wa.y);
      q[2]=(short)f2bf(a.z*wa.z);  q[3]=(short)f2bf(a.w*wa.w);
      q[4]=(short)f2bf(a2.x*wa2.x); q[5]=(short)f2bf(a2.y*wa2.y);
      q[6]=(short)f2bf(a2.z*wa2.z); q[7]=(short)f2bf(a2.w*wa2.w);
      qf[c] = q;
    }
  }

  f32x4 of[16];
  #pragma unroll
  for (int t = 0; t < 16; ++t) of[t] = (f32x4){0.f,0.f,0.f,0.f};
  float mx[4] = {-1e30f,-1e30f,-1e30f,-1e30f};
  float ls[4] = {0.f,0.f,0.f,0.f};

  const u16* kslab = Pbf  + (size_t)b * NP * ND;   // row-major [j][d]
  const u16* vslab = PbfT + (size_t)b * ND * NP;   // d-major  [d][j]

  uint4 kreg[8], vreg[8];                          // staging regs (64 VGPR)

  // coalesced loads: K round r -> rows j=r*8+l7, chunk ck=wave*8+l3
  //                  V round r -> rows d=(r*4+wave)*8+l7, chunk c=l3
  auto loadKV = [&](int kt){
    const int kbase = kt * 64;
    #pragma unroll
    for (int r = 0; r < 8; ++r){
      int j = r * 8 + l7, ck = wave * 8 + l3;
      kreg[r] = *(const uint4*)(kslab + (size_t)(kbase + j) * ND + ck * 8);
    }
    #pragma unroll
    for (int r = 0; r < 8; ++r){
      int d = (r * 4 + wave) * 8 + l7;
      vreg[r] = *(const uint4*)(vslab + (size_t)d * NP + kbase + l3 * 8);
    }
  };
  auto writeKV = [&](){
    #pragma unroll
    for (int r = 0; r < 8; ++r){
      int j = r * 8 + l7, ck = wave * 8 + l3;
      *(uint4*)(KtB + ck * 1024 + 16 * (j ^ ((ck & 1) << 4))) = kreg[r];
    }
    #pragma unroll
    for (int r = 0; r < 8; ++r){
      int d = (r * 4 + wave) * 8 + l7;
      *(uint4*)(VtB + l3 * 4096 + 16 * (d ^ ((l3 & 1) << 4))) = vreg[r];
    }
  };

  float sbc[4], sbn[4];
  loadKV(0);
  #pragma unroll
  for (int nt = 0; nt < 4; ++nt) sbc[nt] = sbv[(size_t)b * NP + nt * 16 + lo];

  for (int kt = 0; kt < 16; ++kt){
    if (kt > 0) __syncthreads();     // sync1: all waves done reading tile kt-1
    writeKV();                        // auto vmcnt-wait on kreg/vreg
    __syncthreads();                  // sync2: tile kt visible
    if (kt < 15){
      loadKV(kt + 1);                 // issue next-tile loads; land during compute
      #pragma unroll
      for (int nt = 0; nt < 4; ++nt)
        sbn[nt] = sbv[(size_t)b * NP + (kt + 1) * 64 + nt * 16 + lo];
    }

    // ---- S = Q K^T (4 col-tiles of 16 keys) ----
    f32x4 s[4];
    #pragma unroll
    for (int nt = 0; nt < 4; ++nt){
      f32x4 acc = (f32x4){0.f,0.f,0.f,0.f};
      #pragma unroll
      for (int c = 0; c < 8; ++c){
        int ck = 4 * c + hi;
        int ad = ck * 1024 + ((((nt << 4) + lo) ^ ((ck & 1) << 4)) << 4);
        bf16x8 kf = *(const bf16x8*)(KtB + ad);
        acc = __builtin_amdgcn_mfma_f32_16x16x32_bf16(qf[c], kf, acc, 0, 0, 0);
      }
      s[nt] = acc;
      float sv = sbc[nt];
      #pragma unroll
      for (int r = 0; r < 4; ++r) s[nt][r] += sv;
    }

    // ---- deferred online softmax ----
    float md = -1e30f;
    #pragma unroll
    for (int nt = 0; nt < 4; ++nt)
      #pragma unroll
      for (int r = 0; r < 4; ++r) md = fmaxf(md, s[nt][r] - mx[r]);
    if (!__all(md <= 8.f)){
      // slow path: proper row maxima + rescale (tile 0, rare after)
      float scale[4];
      #pragma unroll
      for (int r = 0; r < 4; ++r){
        float v = fmaxf(fmaxf(s[0][r], s[1][r]), fmaxf(s[2][r], s[3][r]));
        v = fmaxf(v, __shfl_xor(v, 1, 64));
        v = fmaxf(v, __shfl_xor(v, 2, 64));
        v = fmaxf(v, __shfl_xor(v, 4, 64));
        v = fmaxf(v, __shfl_xor(v, 8, 64));
        float mnew = fmaxf(mx[r], v);
        scale[r] = __expf(mx[r] - mnew);
        mx[r] = mnew;
        ls[r] *= scale[r];
      }
      #pragma unroll
      for (int t = 0; t < 16; ++t)
        #pragma unroll
        for (int r = 0; r < 4; ++r) of[t][r] *= scale[r];
    }
    // common path: exp, per-lane partial sums, repack (p bounded by e^8)
    #pragma unroll
    for (int nt = 0; nt < 4; ++nt)
      #pragma unroll
      for (int r = 0; r < 4; ++r){
        float pv = __expf(s[nt][r] - mx[r]);
        ls[r] += pv;
        Sp[wave][4 * hi + r][16 * nt + lo] = f2bf(pv);
      }

    // ---- O += P V (V from conflict-free LDS) ----
    #pragma unroll
    for (int kk = 0; kk < 2; ++kk){
      bf16x8 pa = *(const bf16x8*)&Sp[wave][lo][32 * kk + 8 * hi];
      int c = 4 * kk + hi;
      int cb = c * 4096, cs = (c & 1) << 4;
      #pragma unroll
      for (int t = 0; t < 16; ++t){
        int ad = cb + ((((t << 4) + lo) ^ cs) << 4);
        bf16x8 vb = *(const bf16x8*)(VtB + ad);
        of[t] = __builtin_amdgcn_mfma_f32_16x16x32_bf16(pa, vb, of[t], 0, 0, 0);
      }
    }
    sbc[0] = sbn[0]; sbc[1] = sbn[1]; sbc[2] = sbn[2]; sbc[3] = sbn[3];
  }

  // ---- epilogue: one cross-lane ls reduce, O /= l, store bf16 ----
  #pragma unroll
  for (int r = 0; r < 4; ++r){
    ls[r] += __shfl_xor(ls[r], 1, 64);
    ls[r] += __shfl_xor(ls[r], 2, 64);
    ls[r] += __shfl_xor(ls[r], 4, 64);
    ls[r] += __shfl_xor(ls[r], 8, 64);
  }
  const int qrow = q0 + wave * 16;
  #pragma unroll
  for (int t = 0; t < 16; ++t){
    #pragma unroll
    for (int r = 0; r < 4; ++r){
      float o = of[t][r] / ls[r];
      attnb[((size_t)b * NP + qrow + 4 * hi + r) * ND + 16 * t + lo] = f2bf(o);
    }
  }
}

// ---------------- MLP: proper GEMM, M-tile 128, fused gate epilogue --------------
// NOTE: acc[3][8] = 96 VGPRs of accumulator. __launch_bounds__ min-waves MUST stay
// at 2 (VGPR budget 256): round-5's (256,4) capped the allocator at 64 VGPR and
// spilled all accumulators to scratch (WRITE_SIZE 33 -> 325 MB, 18 -> 136 us).
__launch_bounds__(256, 2)
__global__ void mlp_kernel(const u16* __restrict__ Pbf, const u16* __restrict__ attnb,
                           const u16* __restrict__ Wp,
                           const float* __restrict__ b1, const float* __restrict__ b2,
                           const float* __restrict__ b3, float* __restrict__ out){
  const int p    = blockIdx.x;
  const int swz  = ((p & 7) << 7) | (p >> 3);     // XCD-chunked
  const int mt   = swz >> 2, cg = swz & 3;
  const int tid  = threadIdx.x;
  const int wave = tid >> 6, lane = tid & 63, lo = lane & 15, hi = lane >> 4;
  const int tq   = 4 * cg + wave;
  const int m0   = mt * 128;

  __shared__ __align__(16) u16 Ab[2][128 * 64];   // 2 x 16 KB, swizzled

  f32x4 acc[3][8];
  #pragma unroll
  for (int e = 0; e < 3; ++e)
    #pragma unroll
    for (int m = 0; m < 8; ++m) acc[e][m] = (f32x4){0.f,0.f,0.f,0.f};

  auto stage = [&](int s, int buf){
    const u16* xs = (s < 4) ? (Pbf   + (size_t)m0 * ND + s * 64)
                            : (attnb + (size_t)m0 * ND + (s - 4) * 64);
    char* dst = (char*)Ab[buf];
    #pragma unroll
    for (int it = 0; it < 4; ++it){
      int off = it * 4096 + wave * 1024 + lane * 16;   // physical LDS byte
      int row = off >> 7;                               // 128B per row
      int cl  = (off & 127) ^ ((row & 7) << 4);         // logical byte in row
      glds16((const char*)(xs + (size_t)row * ND) + cl, dst + it * 4096 + wave * 1024);
    }
  };

  stage(0, 0);
  __syncthreads();

  for (int s = 0; s < 8; ++s){
    if (s < 7) stage(s + 1, (s + 1) & 1);
    const char* ab = (const char*)Ab[s & 1];
    #pragma unroll
    for (int cc = 0; cc < 2; ++cc){
      const int c = 2 * s + cc;
      bf16x8 wf[3];
      #pragma unroll
      for (int e = 0; e < 3; ++e)
        wf[e] = *(const bf16x8*)(Wp + ((size_t)((tq + 16 * e) * 16 + c) * 64 + lane) * 8);
      #pragma unroll
      for (int m = 0; m < 8; ++m){
        int row = 16 * m + lo;
        bf16x8 af = *(const bf16x8*)(ab + row * 128 + ((64 * cc + 16 * hi) ^ ((row & 7) << 4)));
        #pragma unroll
        for (int e = 0; e < 3; ++e)
          acc[e][m] = __builtin_amdgcn_mfma_f32_16x16x32_bf16(af, wf[e], acc[e][m], 0, 0, 0);
      }
    }
    __syncthreads();
  }

  // ---- fused gate epilogue ----
  const int d = 16 * tq + lo;
  const float bb1 = b1[d], bb2 = b2[d], bb3 = b3[d];
  #pragma unroll
  for (int m = 0; m < 8; ++m){
    #pragma unroll
    for (int r = 0; r < 4; ++r){
      const int row = m0 + 16 * m + 4 * hi + r;
      float y1 = acc[0][m][r] + bb1;
      float y2 = acc[1][m][r] + bb2;
      float y3 = acc[2][m][r] + bb3;
      float pv = bf2f(Pbf[(size_t)row * ND + d]);
      float e2 = __expf(2.f * y1);
      float z  = (e2 - 1.f) / (e2 + 1.f);          // tanh
      float rr = 1.f / (1.f + __expf(-y2));        // sigmoid
      float ff = 1.f / (1.f + __expf(-y3));        // sigmoid
      out[(size_t)row * ND + d] = rr * pv + ff * z;
    }
  }
}

extern "C" void kernel_launch(void* const* d_in, const int* in_sizes, int n_in,
                              void* d_out, int out_size, void* d_ws, size_t ws_size,
                              hipStream_t stream){
  const float* P  = (const float*)d_in[0];
  const float* wi = (const float*)d_in[1];
  const float* w1 = (const float*)d_in[2];
  const float* w2 = (const float*)d_in[3];
  const float* w3 = (const float*)d_in[4];
  const float* b1 = (const float*)d_in[5];
  const float* b2 = (const float*)d_in[6];
  const float* b3 = (const float*)d_in[7];
  float* out = (float*)d_out;

  char* ws = (char*)d_ws;
  u16*   Pbf   = (u16*)  (ws);                        // 16 MB
  u16*   PbfT  = (u16*)  (ws + (16u << 20));          // 16 MB
  u16*   attnb = (u16*)  (ws + (32u << 20));          // 16 MB
  u16*   Wp    = (u16*)  (ws + (48u << 20));          // 768 KB packed fragments
  float* sbv   = (float*)(ws + (49u << 20));          // 128 KB

  prep_rows<<<8192, 256, 0, stream>>>(P, wi, Pbf, sbv);
  prep_w<<<48, 256, 0, stream>>>(w1, w2, w3, Wp);
  transpose_p<<<dim3(16, 4, 32), 256, 0, stream>>>(Pbf, PbfT);
  attn_kernel<<<512, 256, 0, stream>>>(P, wi, Pbf, PbfT, sbv, attnb);
  mlp_kernel<<<1024, 256, 0, stream>>>(Pbf, attnb, Wp, b1, b2, b3, out);
}

// Round 9
// 119.752 us; speedup vs baseline: 2.1624x; 2.0884x over previous
//
#include <hip/hip_runtime.h>
#include <hip/hip_bf16.h>

typedef unsigned short u16;
typedef unsigned int   u32;

using bf16x8 = __attribute__((ext_vector_type(8))) short;  // 8 bf16 in 4 VGPRs
using f32x4  = __attribute__((ext_vector_type(4))) float;  // MFMA accumulator

#define NB 32
#define NP 1024
#define ND 256

__device__ __forceinline__ u16 f2bf(float x){
  u32 u = __float_as_uint(x);
  u += 0x7FFFu + ((u >> 16) & 1u);   // round-to-nearest-even
  return (u16)(u >> 16);
}

__device__ __forceinline__ float bf2f(u16 x){
  return __uint_as_float((u32)x << 16);
}

__device__ __forceinline__ void glds16(const void* g, void* l){
  __builtin_amdgcn_global_load_lds((const __attribute__((address_space(1))) void*)g,
                                   (__attribute__((address_space(3))) void*)l, 16, 0, 0);
}

// ---------------- prep 1: Pbf = bf16(P), sbv[row] = P[row,:] . wb ----------------
__global__ void prep_rows(const float* __restrict__ P, const float* __restrict__ wi,
                          u16* __restrict__ Pbf, float* __restrict__ sbv){
  const int row  = blockIdx.x * 4 + (threadIdx.x >> 6);   // one wave per row
  const int lane = threadIdx.x & 63;
  const float4 p  = *(const float4*)(P  + (size_t)row * ND + lane * 4);
  const float4 wb = *(const float4*)(wi + ND + lane * 4);  // wb = wi[256:512]
  ushort4 pb;
  pb.x = f2bf(p.x); pb.y = f2bf(p.y); pb.z = f2bf(p.z); pb.w = f2bf(p.w);
  *(ushort4*)(Pbf + (size_t)row * ND + lane * 4) = pb;
  float s = p.x*wb.x + p.y*wb.y + p.z*wb.z + p.w*wb.w;
  #pragma unroll
  for (int m = 1; m < 64; m <<= 1) s += __shfl_xor(s, m, 64);
  if (lane == 0) sbv[row] = s;
}

// ------- prep 2: pack W fragment-major: Wp[((t*16+c)*64+lane)*8 + e] -------------
__global__ void prep_w(const float* __restrict__ w1, const float* __restrict__ w2,
                       const float* __restrict__ w3, u16* __restrict__ Wp){
  const int t = blockIdx.x;                       // 0..47
  const float* w = (t < 16) ? w1 : ((t < 32) ? w2 : w3);
  const int tid = threadIdx.x;
  #pragma unroll
  for (int j = 0; j < 4; ++j){
    int item = tid + 256 * j;                     // c*64 + lane
    int c = item >> 6, lane = item & 63;
    int ncol = ((t & 15) << 4) + (lane & 15);
    int k0 = 32 * c + 8 * (lane >> 4);
    u16 tmp[8];
    #pragma unroll
    for (int e = 0; e < 8; ++e) tmp[e] = f2bf(w[(size_t)(k0 + e) * 256 + ncol]);
    *(uint4*)(Wp + ((size_t)(t * 16 + c) * 64 + lane) * 8) = *(uint4*)tmp;
  }
}

// ---------------- prep 3: PbfT[b][d][j] = Pbf[b][j][d] (64x64 LDS tiles) ---------
__global__ void transpose_p(const u16* __restrict__ Pbf, u16* __restrict__ PbfT){
  const int b = blockIdx.z, jt = blockIdx.x, dt = blockIdx.y;
  __shared__ u16 T[64][72];
  const int tid = threadIdx.x;
  #pragma unroll
  for (int it = 0; it < 2; ++it){
    int cc = tid + 256 * it;               // 0..511: 64 j-rows x 8 chunks
    int j = cc >> 3, c8 = cc & 7;
    uint4 v = *(const uint4*)(Pbf + ((size_t)b * NP + jt * 64 + j) * ND + dt * 64 + c8 * 8);
    *(uint4*)&T[j][c8 * 8] = v;
  }
  __syncthreads();
  #pragma unroll
  for (int it = 0; it < 2; ++it){
    int cc = tid + 256 * it;               // 64 d-rows x 8 chunks
    int d = cc >> 3, c8 = cc & 7;
    u16 tmp[8];
    #pragma unroll
    for (int k = 0; k < 8; ++k) tmp[k] = T[c8 * 8 + k][d];
    *(uint4*)(PbfT + ((size_t)b * ND + dt * 64 + d) * NP + jt * 64 + c8 * 8) = *(uint4*)tmp;
  }
}

// ---------------- attention: QBLK=64 (4 waves), KBLK=64, glds, split barriers ----
// Layouts with BOTH coalesced glds source AND conflict-free b128 reads:
//   K: phys = j*512 + 16*(ck ^ ((j&7)<<2))       ck = 16B d-chunk 0..31, j = 0..63
//      glds wave-instr = 2 full rows (coalesced); QK read quad = 4*(c^(lo&7))+hi
//      -> 32 distinct quads x 2 lanes (conflict-free).
//   V: phys = d*128 + 16*(kc ^ (((d>>2)&3)<<1))  kc = 16B key-chunk 0..7, d = 0..255
//      glds wave-instr = 8 full 128B rows (coalesced); PV read -> 2 lanes/quad.
// (r2-r3 layout was coalesced but 8-way conflicted (XOR collided with hi bank
//  bits); r4-r6 layout was conflict-free but staged 64-line scattered. This has
//  both.) Split-barrier pipeline: stage K(t+1) after barrier1 (drained by
//  barrier2 across softmax+PV); stage V(t+1) after barrier2 (drained by next
//  barrier1 across QK^T). 2 barriers/tile, no exposed stage latency, no staging
//  registers (r8's reg-staging spilled: 500 MB scratch).
__launch_bounds__(256, 2)
__global__ void attn_kernel(const float* __restrict__ P, const float* __restrict__ wi,
                            const u16* __restrict__ Pbf, const u16* __restrict__ PbfT,
                            const float* __restrict__ sbv, u16* __restrict__ attnb){
  const int p    = blockIdx.x;
  const int bid  = ((p & 7) << 6) | (p >> 3);     // 64 consecutive bids per XCD
  const int b    = bid >> 4;
  const int q0   = (bid & 15) << 6;
  const int tid  = threadIdx.x;
  const int wave = tid >> 6, lane = tid & 63, lo = lane & 15, hi = lane >> 4;

  __shared__ __align__(16) u16 KtA[64 * 256];     // 32 KB
  __shared__ __align__(16) u16 VtA[256 * 64];     // 32 KB
  __shared__ __align__(16) u16 Sp[4][16][72];     // 9.2 KB
  char* KtB = (char*)KtA;
  char* VtB = (char*)VtA;

  // ---- Q fragments (A-operand): q = P * wc, bf16, in regs ----
  bf16x8 qf[8];
  {
    const int qrow = q0 + wave * 16 + lo;
    const float* prow = P  + ((size_t)b * NP + qrow) * ND;
    const float* wcp  = wi + 512;
    #pragma unroll
    for (int c = 0; c < 8; ++c){
      const int d0 = 32 * c + 8 * hi;
      float4 a  = *(const float4*)(prow + d0);
      float4 a2 = *(const float4*)(prow + d0 + 4);
      float4 wa  = *(const float4*)(wcp + d0);
      float4 wa2 = *(const float4*)(wcp + d0 + 4);
      bf16x8 q;
      q[0]=(short)f2bf(a.x*wa.x);  q[1]=(short)f2bf(a.y*wa.y);
      q[2]=(short)f2bf(a.z*wa.z);  q[3]=(short)f2bf(a.w*wa.w);
      q[4]=(short)f2bf(a2.x*wa2.x); q[5]=(short)f2bf(a2.y*wa2.y);
      q[6]=(short)f2bf(a2.z*wa2.z); q[7]=(short)f2bf(a2.w*wa2.w);
      qf[c] = q;
    }
  }

  f32x4 of[16];
  #pragma unroll
  for (int t = 0; t < 16; ++t) of[t] = (f32x4){0.f,0.f,0.f,0.f};
  float mx[4] = {-1e30f,-1e30f,-1e30f,-1e30f};
  float ls[4] = {0.f,0.f,0.f,0.f};

  const u16* kslab = Pbf  + (size_t)b * NP * ND;   // row-major [j][d]
  const u16* vslab = PbfT + (size_t)b * ND * NP;   // d-major  [d][j]

  auto stageK = [&](int kt){
    const int kbase = kt * 64;
    #pragma unroll
    for (int it = 0; it < 8; ++it){
      int off = it * 4096 + tid * 16;             // linear LDS dest byte
      int j   = off >> 9;
      int ck  = ((off >> 4) & 31) ^ ((j & 7) << 2);
      glds16((const char*)(kslab + (size_t)(kbase + j) * ND + ck * 8), KtB + off);
    }
  };
  auto stageV = [&](int kt){
    const int kbase = kt * 64;
    #pragma unroll
    for (int it = 0; it < 8; ++it){
      int off = it * 4096 + tid * 16;
      int d   = off >> 7;
      int kc  = ((off >> 4) & 7) ^ (((d >> 2) & 3) << 1);
      glds16((const char*)(vslab + (size_t)d * NP + kbase + kc * 8), VtB + off);
    }
  };

  float sbc[4], sbn[4];
  stageK(0);
  stageV(0);
  #pragma unroll
  for (int nt = 0; nt < 4; ++nt) sbc[nt] = sbv[(size_t)b * NP + nt * 16 + lo];
  __syncthreads();                                 // drain: K0,V0 valid

  for (int kt = 0; kt < 16; ++kt){
    // ---- S = Q K^T (reads Kt; V(kt) glds drained by this iter's entry sync) ----
    f32x4 s[4];
    #pragma unroll
    for (int nt = 0; nt < 4; ++nt){
      f32x4 acc = (f32x4){0.f,0.f,0.f,0.f};
      #pragma unroll
      for (int c = 0; c < 8; ++c){
        int j  = nt * 16 + lo;
        int ad = j * 512 + ((((4 * c + hi)) ^ ((j & 7) << 2)) << 4);
        bf16x8 kf = *(const bf16x8*)(KtB + ad);
        acc = __builtin_amdgcn_mfma_f32_16x16x32_bf16(qf[c], kf, acc, 0, 0, 0);
      }
      s[nt] = acc;
      float sv = sbc[nt];
      #pragma unroll
      for (int r = 0; r < 4; ++r) s[nt][r] += sv;
    }

    __syncthreads();                  // barrier1: all waves done reading Kt
    if (kt < 15) stageK(kt + 1);      // in flight across softmax+PV; drained at barrier2

    // ---- deferred online softmax ----
    float md = -1e30f;
    #pragma unroll
    for (int nt = 0; nt < 4; ++nt)
      #pragma unroll
      for (int r = 0; r < 4; ++r) md = fmaxf(md, s[nt][r] - mx[r]);
    if (!__all(md <= 8.f)){
      // slow path: proper row maxima + rescale (tile 0, rare after)
      float scale[4];
      #pragma unroll
      for (int r = 0; r < 4; ++r){
        float v = fmaxf(fmaxf(s[0][r], s[1][r]), fmaxf(s[2][r], s[3][r]));
        v = fmaxf(v, __shfl_xor(v, 1, 64));
        v = fmaxf(v, __shfl_xor(v, 2, 64));
        v = fmaxf(v, __shfl_xor(v, 4, 64));
        v = fmaxf(v, __shfl_xor(v, 8, 64));
        float mnew = fmaxf(mx[r], v);
        scale[r] = __expf(mx[r] - mnew);
        mx[r] = mnew;
        ls[r] *= scale[r];
      }
      #pragma unroll
      for (int t = 0; t < 16; ++t)
        #pragma unroll
        for (int r = 0; r < 4; ++r) of[t][r] *= scale[r];
    }
    // common path: exp, per-lane partial sums, repack (p bounded by e^8)
    #pragma unroll
    for (int nt = 0; nt < 4; ++nt)
      #pragma unroll
      for (int r = 0; r < 4; ++r){
        float pv = __expf(s[nt][r] - mx[r]);
        ls[r] += pv;
        Sp[wave][4 * hi + r][16 * nt + lo] = f2bf(pv);
      }

    // ---- O += P V (reads Vt; Sp is within-wave, no barrier needed) ----
    #pragma unroll
    for (int kk = 0; kk < 2; ++kk){
      bf16x8 pa = *(const bf16x8*)&Sp[wave][lo][32 * kk + 8 * hi];
      #pragma unroll
      for (int t = 0; t < 16; ++t){
        int d  = 16 * t + lo;
        int ad = d * 128 + ((((4 * kk + hi)) ^ (((d >> 2) & 3) << 1)) << 4);
        bf16x8 vb = *(const bf16x8*)(VtB + ad);
        of[t] = __builtin_amdgcn_mfma_f32_16x16x32_bf16(pa, vb, of[t], 0, 0, 0);
      }
    }

    __syncthreads();                  // barrier2: Vt reads done; drains K(t+1) glds
    if (kt < 15){
      stageV(kt + 1);                 // in flight across next QK^T; drained at barrier1
      #pragma unroll
      for (int nt = 0; nt < 4; ++nt)
        sbn[nt] = sbv[(size_t)b * NP + (kt + 1) * 64 + nt * 16 + lo];
      sbc[0] = sbn[0]; sbc[1] = sbn[1]; sbc[2] = sbn[2]; sbc[3] = sbn[3];
    }
  }

  // ---- epilogue: one cross-lane ls reduce, O /= l, store bf16 ----
  #pragma unroll
  for (int r = 0; r < 4; ++r){
    ls[r] += __shfl_xor(ls[r], 1, 64);
    ls[r] += __shfl_xor(ls[r], 2, 64);
    ls[r] += __shfl_xor(ls[r], 4, 64);
    ls[r] += __shfl_xor(ls[r], 8, 64);
  }
  const int qrow = q0 + wave * 16;
  #pragma unroll
  for (int t = 0; t < 16; ++t){
    #pragma unroll
    for (int r = 0; r < 4; ++r){
      float o = of[t][r] / ls[r];
      attnb[((size_t)b * NP + qrow + 4 * hi + r) * ND + 16 * t + lo] = f2bf(o);
    }
  }
}

// ---------------- MLP: proper GEMM, M-tile 128, fused gate epilogue --------------
// NOTE: acc[3][8] = 96 VGPRs of accumulator. __launch_bounds__ min-waves MUST stay
// at 2 (VGPR budget 256): round-5's (256,4) capped the allocator at 64 VGPR and
// spilled all accumulators to scratch (WRITE_SIZE 33 -> 325 MB, 18 -> 136 us).
__launch_bounds__(256, 2)
__global__ void mlp_kernel(const u16* __restrict__ Pbf, const u16* __restrict__ attnb,
                           const u16* __restrict__ Wp,
                           const float* __restrict__ b1, const float* __restrict__ b2,
                           const float* __restrict__ b3, float* __restrict__ out){
  const int p    = blockIdx.x;
  const int swz  = ((p & 7) << 7) | (p >> 3);     // XCD-chunked
  const int mt   = swz >> 2, cg = swz & 3;
  const int tid  = threadIdx.x;
  const int wave = tid >> 6, lane = tid & 63, lo = lane & 15, hi = lane >> 4;
  const int tq   = 4 * cg + wave;
  const int m0   = mt * 128;

  __shared__ __align__(16) u16 Ab[2][128 * 64];   // 2 x 16 KB, swizzled

  f32x4 acc[3][8];
  #pragma unroll
  for (int e = 0; e < 3; ++e)
    #pragma unroll
    for (int m = 0; m < 8; ++m) acc[e][m] = (f32x4){0.f,0.f,0.f,0.f};

  auto stage = [&](int s, int buf){
    const u16* xs = (s < 4) ? (Pbf   + (size_t)m0 * ND + s * 64)
                            : (attnb + (size_t)m0 * ND + (s - 4) * 64);
    char* dst = (char*)Ab[buf];
    #pragma unroll
    for (int it = 0; it < 4; ++it){
      int off = it * 4096 + wave * 1024 + lane * 16;   // physical LDS byte
      int row = off >> 7;                               // 128B per row
      int cl  = (off & 127) ^ ((row & 7) << 4);         // logical byte in row
      glds16((const char*)(xs + (size_t)row * ND) + cl, dst + it * 4096 + wave * 1024);
    }
  };

  stage(0, 0);
  __syncthreads();

  for (int s = 0; s < 8; ++s){
    if (s < 7) stage(s + 1, (s + 1) & 1);
    const char* ab = (const char*)Ab[s & 1];
    #pragma unroll
    for (int cc = 0; cc < 2; ++cc){
      const int c = 2 * s + cc;
      bf16x8 wf[3];
      #pragma unroll
      for (int e = 0; e < 3; ++e)
        wf[e] = *(const bf16x8*)(Wp + ((size_t)((tq + 16 * e) * 16 + c) * 64 + lane) * 8);
      #pragma unroll
      for (int m = 0; m < 8; ++m){
        int row = 16 * m + lo;
        bf16x8 af = *(const bf16x8*)(ab + row * 128 + ((64 * cc + 16 * hi) ^ ((row & 7) << 4)));
        #pragma unroll
        for (int e = 0; e < 3; ++e)
          acc[e][m] = __builtin_amdgcn_mfma_f32_16x16x32_bf16(af, wf[e], acc[e][m], 0, 0, 0);
      }
    }
    __syncthreads();
  }

  // ---- fused gate epilogue ----
  const int d = 16 * tq + lo;
  const float bb1 = b1[d], bb2 = b2[d], bb3 = b3[d];
  #pragma unroll
  for (int m = 0; m < 8; ++m){
    #pragma unroll
    for (int r = 0; r < 4; ++r){
      const int row = m0 + 16 * m + 4 * hi + r;
      float y1 = acc[0][m][r] + bb1;
      float y2 = acc[1][m][r] + bb2;
      float y3 = acc[2][m][r] + bb3;
      float pv = bf2f(Pbf[(size_t)row * ND + d]);
      float e2 = __expf(2.f * y1);
      float z  = (e2 - 1.f) / (e2 + 1.f);          // tanh
      float rr = 1.f / (1.f + __expf(-y2));        // sigmoid
      float ff = 1.f / (1.f + __expf(-y3));        // sigmoid
      out[(size_t)row * ND + d] = rr * pv + ff * z;
    }
  }
}

extern "C" void kernel_launch(void* const* d_in, const int* in_sizes, int n_in,
                              void* d_out, int out_size, void* d_ws, size_t ws_size,
                              hipStream_t stream){
  const float* P  = (const float*)d_in[0];
  const float* wi = (const float*)d_in[1];
  const float* w1 = (const float*)d_in[2];
  const float* w2 = (const float*)d_in[3];
  const float* w3 = (const float*)d_in[4];
  const float* b1 = (const float*)d_in[5];
  const float* b2 = (const float*)d_in[6];
  const float* b3 = (const float*)d_in[7];
  float* out = (float*)d_out;

  char* ws = (char*)d_ws;
  u16*   Pbf   = (u16*)  (ws);                        // 16 MB
  u16*   PbfT  = (u16*)  (ws + (16u << 20));          // 16 MB
  u16*   attnb = (u16*)  (ws + (32u << 20));          // 16 MB
  u16*   Wp    = (u16*)  (ws + (48u << 20));          // 768 KB packed fragments
  float* sbv   = (float*)(ws + (49u << 20));          // 128 KB

  prep_rows<<<8192, 256, 0, stream>>>(P, wi, Pbf, sbv);
  prep_w<<<48, 256, 0, stream>>>(w1, w2, w3, Wp);
  transpose_p<<<dim3(16, 4, 32), 256, 0, stream>>>(Pbf, PbfT);
  attn_kernel<<<512, 256, 0, stream>>>(P, wi, Pbf, PbfT, sbv, attnb);
  mlp_kernel<<<1024, 256, 0, stream>>>(Pbf, attnb, Wp, b1, b2, b3, out);
}

// Round 10
// 117.350 us; speedup vs baseline: 2.2066x; 1.0205x over previous
//
#include <hip/hip_runtime.h>
#include <hip/hip_bf16.h>

typedef unsigned short u16;
typedef unsigned int   u32;

using bf16x8 = __attribute__((ext_vector_type(8))) short;  // 8 bf16 in 4 VGPRs
using f32x4  = __attribute__((ext_vector_type(4))) float;  // MFMA accumulator

#define NB 32
#define NP 1024
#define ND 256

__device__ __forceinline__ u16 f2bf(float x){
  u32 u = __float_as_uint(x);
  u += 0x7FFFu + ((u >> 16) & 1u);   // round-to-nearest-even
  return (u16)(u >> 16);
}

__device__ __forceinline__ float bf2f(u16 x){
  return __uint_as_float((u32)x << 16);
}

__device__ __forceinline__ void glds16(const void* g, void* l){
  __builtin_amdgcn_global_load_lds((const __attribute__((address_space(1))) void*)g,
                                   (__attribute__((address_space(3))) void*)l, 16, 0, 0);
}

// ---------------- prep 1: Pbf = bf16(P), sbv[row] = P[row,:] . wb ----------------
__global__ void prep_rows(const float* __restrict__ P, const float* __restrict__ wi,
                          u16* __restrict__ Pbf, float* __restrict__ sbv){
  const int row  = blockIdx.x * 4 + (threadIdx.x >> 6);   // one wave per row
  const int lane = threadIdx.x & 63;
  const float4 p  = *(const float4*)(P  + (size_t)row * ND + lane * 4);
  const float4 wb = *(const float4*)(wi + ND + lane * 4);  // wb = wi[256:512]
  ushort4 pb;
  pb.x = f2bf(p.x); pb.y = f2bf(p.y); pb.z = f2bf(p.z); pb.w = f2bf(p.w);
  *(ushort4*)(Pbf + (size_t)row * ND + lane * 4) = pb;
  float s = p.x*wb.x + p.y*wb.y + p.z*wb.z + p.w*wb.w;
  #pragma unroll
  for (int m = 1; m < 64; m <<= 1) s += __shfl_xor(s, m, 64);
  if (lane == 0) sbv[row] = s;
}

// ------- prep 2: pack W fragment-major: Wp[((t*16+c)*64+lane)*8 + e] -------------
__global__ void prep_w(const float* __restrict__ w1, const float* __restrict__ w2,
                       const float* __restrict__ w3, u16* __restrict__ Wp){
  const int t = blockIdx.x;                       // 0..47
  const float* w = (t < 16) ? w1 : ((t < 32) ? w2 : w3);
  const int tid = threadIdx.x;
  #pragma unroll
  for (int j = 0; j < 4; ++j){
    int item = tid + 256 * j;                     // c*64 + lane
    int c = item >> 6, lane = item & 63;
    int ncol = ((t & 15) << 4) + (lane & 15);
    int k0 = 32 * c + 8 * (lane >> 4);
    u16 tmp[8];
    #pragma unroll
    for (int e = 0; e < 8; ++e) tmp[e] = f2bf(w[(size_t)(k0 + e) * 256 + ncol]);
    *(uint4*)(Wp + ((size_t)(t * 16 + c) * 64 + lane) * 8) = *(uint4*)tmp;
  }
}

// ---------------- prep 3: PbfT[b][d][j] = Pbf[b][j][d] (64x64 LDS tiles) ---------
__global__ void transpose_p(const u16* __restrict__ Pbf, u16* __restrict__ PbfT){
  const int b = blockIdx.z, jt = blockIdx.x, dt = blockIdx.y;
  __shared__ u16 T[64][72];
  const int tid = threadIdx.x;
  #pragma unroll
  for (int it = 0; it < 2; ++it){
    int cc = tid + 256 * it;               // 0..511: 64 j-rows x 8 chunks
    int j = cc >> 3, c8 = cc & 7;
    uint4 v = *(const uint4*)(Pbf + ((size_t)b * NP + jt * 64 + j) * ND + dt * 64 + c8 * 8);
    *(uint4*)&T[j][c8 * 8] = v;
  }
  __syncthreads();
  #pragma unroll
  for (int it = 0; it < 2; ++it){
    int cc = tid + 256 * it;               // 64 d-rows x 8 chunks
    int d = cc >> 3, c8 = cc & 7;
    u16 tmp[8];
    #pragma unroll
    for (int k = 0; k < 8; ++k) tmp[k] = T[c8 * 8 + k][d];
    *(uint4*)(PbfT + ((size_t)b * ND + dt * 64 + d) * NP + jt * 64 + c8 * 8) = *(uint4*)tmp;
  }
}

// ---------------- attention: QBLK=64 (4 waves), KBLK=64, glds, split barriers ----
// Bank model (validated r4-vs-r9: 262K vs 8.65M conflicts): b128 is conflict-free
// iff each aligned 8-lane group covers all 8 bank-quads, i.e. quad=(addr/16)%8
// must be a bijection of (lo&7) at fixed hi. Layouts (both-sides, rule #21):
//   K: phys = j*512 + 16*(ck ^ (j&7))   -> read quad = (4(c&1)+hi)^(lo&7)  OK
//      glds source = whole 512B rows permuted within (coalesced, 2 rows/instr)
//   V: phys = d*128 + 16*(kc ^ (d&7))   -> read quad = (4kk+hi)^(lo&7)     OK
//      glds source = whole 128B rows permuted within (coalesced, 8 rows/instr)
// Split-barrier pipeline (r9): stage K(t+1) after barrier1 (drains at barrier2
// across softmax+PV); stage V(t+1) after barrier2 (drains at next barrier1
// across QK^T). 2 barriers/tile, no staging registers.
__launch_bounds__(256, 2)
__global__ void attn_kernel(const float* __restrict__ P, const float* __restrict__ wi,
                            const u16* __restrict__ Pbf, const u16* __restrict__ PbfT,
                            const float* __restrict__ sbv, u16* __restrict__ attnb){
  const int p    = blockIdx.x;
  const int bid  = ((p & 7) << 6) | (p >> 3);     // 64 consecutive bids per XCD
  const int b    = bid >> 4;
  const int q0   = (bid & 15) << 6;
  const int tid  = threadIdx.x;
  const int wave = tid >> 6, lane = tid & 63, lo = lane & 15, hi = lane >> 4;

  __shared__ __align__(16) u16 KtA[64 * 256];     // 32 KB
  __shared__ __align__(16) u16 VtA[256 * 64];     // 32 KB
  __shared__ __align__(16) u16 Sp[4][16][72];     // 9.2 KB
  char* KtB = (char*)KtA;
  char* VtB = (char*)VtA;

  // ---- Q fragments (A-operand): q = P * wc, bf16, in regs ----
  bf16x8 qf[8];
  {
    const int qrow = q0 + wave * 16 + lo;
    const float* prow = P  + ((size_t)b * NP + qrow) * ND;
    const float* wcp  = wi + 512;
    #pragma unroll
    for (int c = 0; c < 8; ++c){
      const int d0 = 32 * c + 8 * hi;
      float4 a  = *(const float4*)(prow + d0);
      float4 a2 = *(const float4*)(prow + d0 + 4);
      float4 wa  = *(const float4*)(wcp + d0);
      float4 wa2 = *(const float4*)(wcp + d0 + 4);
      bf16x8 q;
      q[0]=(short)f2bf(a.x*wa.x);  q[1]=(short)f2bf(a.y*wa.y);
      q[2]=(short)f2bf(a.z*wa.z);  q[3]=(short)f2bf(a.w*wa.w);
      q[4]=(short)f2bf(a2.x*wa2.x); q[5]=(short)f2bf(a2.y*wa2.y);
      q[6]=(short)f2bf(a2.z*wa2.z); q[7]=(short)f2bf(a2.w*wa2.w);
      qf[c] = q;
    }
  }

  f32x4 of[16];
  #pragma unroll
  for (int t = 0; t < 16; ++t) of[t] = (f32x4){0.f,0.f,0.f,0.f};
  float mx[4] = {-1e30f,-1e30f,-1e30f,-1e30f};
  float ls[4] = {0.f,0.f,0.f,0.f};

  const u16* kslab = Pbf  + (size_t)b * NP * ND;   // row-major [j][d]
  const u16* vslab = PbfT + (size_t)b * ND * NP;   // d-major  [d][j]

  auto stageK = [&](int kt){
    const int kbase = kt * 64;
    #pragma unroll
    for (int it = 0; it < 8; ++it){
      int off = it * 4096 + tid * 16;             // linear LDS dest byte
      int j   = off >> 9;
      int ck  = ((off >> 4) & 31) ^ (j & 7);
      glds16((const char*)(kslab + (size_t)(kbase + j) * ND + ck * 8), KtB + off);
    }
  };
  auto stageV = [&](int kt){
    const int kbase = kt * 64;
    #pragma unroll
    for (int it = 0; it < 8; ++it){
      int off = it * 4096 + tid * 16;
      int d   = off >> 7;
      int kc  = ((off >> 4) & 7) ^ (d & 7);
      glds16((const char*)(vslab + (size_t)d * NP + kbase + kc * 8), VtB + off);
    }
  };

  float sbc[4], sbn[4];
  stageK(0);
  stageV(0);
  #pragma unroll
  for (int nt = 0; nt < 4; ++nt) sbc[nt] = sbv[(size_t)b * NP + nt * 16 + lo];
  __syncthreads();                                 // drain: K0,V0 valid

  for (int kt = 0; kt < 16; ++kt){
    // ---- S = Q K^T (reads Kt; V(kt) glds drained by this iter's entry sync) ----
    f32x4 s[4];
    #pragma unroll
    for (int nt = 0; nt < 4; ++nt){
      f32x4 acc = (f32x4){0.f,0.f,0.f,0.f};
      #pragma unroll
      for (int c = 0; c < 8; ++c){
        int j  = nt * 16 + lo;
        int ad = j * 512 + (((4 * c + hi) ^ (j & 7)) << 4);
        bf16x8 kf = *(const bf16x8*)(KtB + ad);
        acc = __builtin_amdgcn_mfma_f32_16x16x32_bf16(qf[c], kf, acc, 0, 0, 0);
      }
      s[nt] = acc;
      float sv = sbc[nt];
      #pragma unroll
      for (int r = 0; r < 4; ++r) s[nt][r] += sv;
    }

    __syncthreads();                  // barrier1: all waves done reading Kt
    if (kt < 15) stageK(kt + 1);      // in flight across softmax+PV; drained at barrier2

    // ---- deferred online softmax ----
    float md = -1e30f;
    #pragma unroll
    for (int nt = 0; nt < 4; ++nt)
      #pragma unroll
      for (int r = 0; r < 4; ++r) md = fmaxf(md, s[nt][r] - mx[r]);
    if (!__all(md <= 8.f)){
      // slow path: proper row maxima + rescale (tile 0, rare after)
      float scale[4];
      #pragma unroll
      for (int r = 0; r < 4; ++r){
        float v = fmaxf(fmaxf(s[0][r], s[1][r]), fmaxf(s[2][r], s[3][r]));
        v = fmaxf(v, __shfl_xor(v, 1, 64));
        v = fmaxf(v, __shfl_xor(v, 2, 64));
        v = fmaxf(v, __shfl_xor(v, 4, 64));
        v = fmaxf(v, __shfl_xor(v, 8, 64));
        float mnew = fmaxf(mx[r], v);
        scale[r] = __expf(mx[r] - mnew);
        mx[r] = mnew;
        ls[r] *= scale[r];
      }
      #pragma unroll
      for (int t = 0; t < 16; ++t)
        #pragma unroll
        for (int r = 0; r < 4; ++r) of[t][r] *= scale[r];
    }
    // common path: exp, per-lane partial sums, repack (p bounded by e^8)
    #pragma unroll
    for (int nt = 0; nt < 4; ++nt)
      #pragma unroll
      for (int r = 0; r < 4; ++r){
        float pv = __expf(s[nt][r] - mx[r]);
        ls[r] += pv;
        Sp[wave][4 * hi + r][16 * nt + lo] = f2bf(pv);
      }

    // ---- O += P V (reads Vt; Sp is within-wave, no barrier needed) ----
    #pragma unroll
    for (int kk = 0; kk < 2; ++kk){
      bf16x8 pa = *(const bf16x8*)&Sp[wave][lo][32 * kk + 8 * hi];
      #pragma unroll
      for (int t = 0; t < 16; ++t){
        int d  = 16 * t + lo;
        int ad = d * 128 + (((4 * kk + hi) ^ (d & 7)) << 4);
        bf16x8 vb = *(const bf16x8*)(VtB + ad);
        of[t] = __builtin_amdgcn_mfma_f32_16x16x32_bf16(pa, vb, of[t], 0, 0, 0);
      }
    }

    __syncthreads();                  // barrier2: Vt reads done; drains K(t+1) glds
    if (kt < 15){
      stageV(kt + 1);                 // in flight across next QK^T; drained at barrier1
      #pragma unroll
      for (int nt = 0; nt < 4; ++nt)
        sbn[nt] = sbv[(size_t)b * NP + (kt + 1) * 64 + nt * 16 + lo];
      sbc[0] = sbn[0]; sbc[1] = sbn[1]; sbc[2] = sbn[2]; sbc[3] = sbn[3];
    }
  }

  // ---- epilogue: one cross-lane ls reduce, O /= l, store bf16 ----
  #pragma unroll
  for (int r = 0; r < 4; ++r){
    ls[r] += __shfl_xor(ls[r], 1, 64);
    ls[r] += __shfl_xor(ls[r], 2, 64);
    ls[r] += __shfl_xor(ls[r], 4, 64);
    ls[r] += __shfl_xor(ls[r], 8, 64);
  }
  const int qrow = q0 + wave * 16;
  #pragma unroll
  for (int t = 0; t < 16; ++t){
    #pragma unroll
    for (int r = 0; r < 4; ++r){
      float o = of[t][r] / ls[r];
      attnb[((size_t)b * NP + qrow + 4 * hi + r) * ND + 16 * t + lo] = f2bf(o);
    }
  }
}

// ---------------- MLP: proper GEMM, M-tile 128, fused gate epilogue --------------
// NOTE: acc[3][8] = 96 VGPRs of accumulator. __launch_bounds__ min-waves MUST stay
// at 2 (VGPR budget 256): round-5's (256,4) capped the allocator at 64 VGPR and
// spilled all accumulators to scratch (WRITE_SIZE 33 -> 325 MB, 18 -> 136 us).
__launch_bounds__(256, 2)
__global__ void mlp_kernel(const u16* __restrict__ Pbf, const u16* __restrict__ attnb,
                           const u16* __restrict__ Wp,
                           const float* __restrict__ b1, const float* __restrict__ b2,
                           const float* __restrict__ b3, float* __restrict__ out){
  const int p    = blockIdx.x;
  const int swz  = ((p & 7) << 7) | (p >> 3);     // XCD-chunked
  const int mt   = swz >> 2, cg = swz & 3;
  const int tid  = threadIdx.x;
  const int wave = tid >> 6, lane = tid & 63, lo = lane & 15, hi = lane >> 4;
  const int tq   = 4 * cg + wave;
  const int m0   = mt * 128;

  __shared__ __align__(16) u16 Ab[2][128 * 64];   // 2 x 16 KB, swizzled

  f32x4 acc[3][8];
  #pragma unroll
  for (int e = 0; e < 3; ++e)
    #pragma unroll
    for (int m = 0; m < 8; ++m) acc[e][m] = (f32x4){0.f,0.f,0.f,0.f};

  auto stage = [&](int s, int buf){
    const u16* xs = (s < 4) ? (Pbf   + (size_t)m0 * ND + s * 64)
                            : (attnb + (size_t)m0 * ND + (s - 4) * 64);
    char* dst = (char*)Ab[buf];
    #pragma unroll
    for (int it = 0; it < 4; ++it){
      int off = it * 4096 + wave * 1024 + lane * 16;   // physical LDS byte
      int row = off >> 7;                               // 128B per row
      int cl  = (off & 127) ^ ((row & 7) << 4);         // logical byte in row
      glds16((const char*)(xs + (size_t)row * ND) + cl, dst + it * 4096 + wave * 1024);
    }
  };

  stage(0, 0);
  __syncthreads();

  for (int s = 0; s < 8; ++s){
    if (s < 7) stage(s + 1, (s + 1) & 1);
    const char* ab = (const char*)Ab[s & 1];
    #pragma unroll
    for (int cc = 0; cc < 2; ++cc){
      const int c = 2 * s + cc;
      bf16x8 wf[3];
      #pragma unroll
      for (int e = 0; e < 3; ++e)
        wf[e] = *(const bf16x8*)(Wp + ((size_t)((tq + 16 * e) * 16 + c) * 64 + lane) * 8);
      #pragma unroll
      for (int m = 0; m < 8; ++m){
        int row = 16 * m + lo;
        bf16x8 af = *(const bf16x8*)(ab + row * 128 + ((64 * cc + 16 * hi) ^ ((row & 7) << 4)));
        #pragma unroll
        for (int e = 0; e < 3; ++e)
          acc[e][m] = __builtin_amdgcn_mfma_f32_16x16x32_bf16(af, wf[e], acc[e][m], 0, 0, 0);
      }
    }
    __syncthreads();
  }

  // ---- fused gate epilogue ----
  const int d = 16 * tq + lo;
  const float bb1 = b1[d], bb2 = b2[d], bb3 = b3[d];
  #pragma unroll
  for (int m = 0; m < 8; ++m){
    #pragma unroll
    for (int r = 0; r < 4; ++r){
      const int row = m0 + 16 * m + 4 * hi + r;
      float y1 = acc[0][m][r] + bb1;
      float y2 = acc[1][m][r] + bb2;
      float y3 = acc[2][m][r] + bb3;
      float pv = bf2f(Pbf[(size_t)row * ND + d]);
      float e2 = __expf(2.f * y1);
      float z  = (e2 - 1.f) / (e2 + 1.f);          // tanh
      float rr = 1.f / (1.f + __expf(-y2));        // sigmoid
      float ff = 1.f / (1.f + __expf(-y3));        // sigmoid
      out[(size_t)row * ND + d] = rr * pv + ff * z;
    }
  }
}

extern "C" void kernel_launch(void* const* d_in, const int* in_sizes, int n_in,
                              void* d_out, int out_size, void* d_ws, size_t ws_size,
                              hipStream_t stream){
  const float* P  = (const float*)d_in[0];
  const float* wi = (const float*)d_in[1];
  const float* w1 = (const float*)d_in[2];
  const float* w2 = (const float*)d_in[3];
  const float* w3 = (const float*)d_in[4];
  const float* b1 = (const float*)d_in[5];
  const float* b2 = (const float*)d_in[6];
  const float* b3 = (const float*)d_in[7];
  float* out = (float*)d_out;

  char* ws = (char*)d_ws;
  u16*   Pbf   = (u16*)  (ws);                        // 16 MB
  u16*   PbfT  = (u16*)  (ws + (16u << 20));          // 16 MB
  u16*   attnb = (u16*)  (ws + (32u << 20));          // 16 MB
  u16*   Wp    = (u16*)  (ws + (48u << 20));          // 768 KB packed fragments
  float* sbv   = (float*)(ws + (49u << 20));          // 128 KB

  prep_rows<<<8192, 256, 0, stream>>>(P, wi, Pbf, sbv);
  prep_w<<<48, 256, 0, stream>>>(w1, w2, w3, Wp);
  transpose_p<<<dim3(16, 4, 32), 256, 0, stream>>>(Pbf, PbfT);
  attn_kernel<<<512, 256, 0, stream>>>(P, wi, Pbf, PbfT, sbv, attnb);
  mlp_kernel<<<1024, 256, 0, stream>>>(Pbf, attnb, Wp, b1, b2, b3, out);
}